// Round 5
// baseline (147.665 us; speedup 1.0000x reference)
//
#include <hip/hip_runtime.h>

// CBOW negative-sampling loss.
// Inputs (setup_inputs order):
//   d_in[0] context   [B, C]  int32
//   d_in[1] target    [B]     int32
//   d_in[2] negatives [B, K]  int32
//   d_in[3] in_emb    [V, D]  f32
//   d_in[4] out_emb   [V, D]  f32
// Output: scalar f32 = -mean_b( log(sig(pos)+eps) + sum_k log(sig(-neg_k)+eps) )
//
// R8: linear L3-warming sweep before the gathers.
// Evidence: FETCH_SIZE (83.7 MB) == compulsory unique-row footprint
// (100k*(1-e^-1.64)*512B + 100k*(1-e^-1.80)*512B ~= 84 MB) -> bytes are
// already minimal; the kernel runs at only 2.2 TB/s because the DRAM-side
// pattern is random 512B chunks (ws poison fill evicts L3 every iter).
// R7's forced 21-deep MLP changed nothing -> throughput-bound, not
// latency-bound. Fix the DRAM efficiency instead: stream BOTH tables
// linearly (coalesced float4, grid-stride, kept alive via empty asm) to
// warm the 256 MiB L3 at linear-stream rate, then gather from L3.
// Gather path itself is byte-identical to R7 (incl. staged loads).

#define VOCAB  100000
#define DIM    128
#define B_TOT  16384
#define CWIN   10
#define K_NEG  10
#define EPS_F  1e-9f

#define BPB    8                    // b's per 256-thread block (8 half-waves)
#define NBLK   (B_TOT / BPB)        // 2048 blocks
#define NTHR   (NBLK * 256)         // 524288 threads total
#define TBL4   (VOCAB * (DIM / 4))  // 3,200,000 float4s per table

__global__ __launch_bounds__(256, 4) void cbow_loss_kernel(
    const int*   __restrict__ context,
    const int*   __restrict__ target,
    const int*   __restrict__ negatives,
    const float* __restrict__ in_emb,
    const float* __restrict__ out_emb,
    float*       __restrict__ partials)    // NBLK floats in ws
{
    const int tid    = threadIdx.x;
    const int halfId = tid >> 5;           // 0..7
    const int sub    = tid & 31;           // lane within half-wave
    const int b      = blockIdx.x * BPB + halfId;

    const float4* in4  = (const float4*)in_emb;
    const float4* out4 = (const float4*)out_emb;

    // ---- index load first: its latency hides under the sweep ----
    // lanes 0..9  -> context[b*10+sub]
    // lanes 10..19-> negatives[b*10+(sub-10)]
    // lane  20    -> target[b]
    int myIdx = 0;
    {
        const int* p  = target;
        int        off = b;
        if (sub < CWIN)                 { p = context;   off = b * CWIN + sub; }
        else if (sub < 2 * CWIN)        { p = negatives; off = b * K_NEG + (sub - CWIN); }
        if (sub <= 2 * CWIN) myIdx = p[off];
    }

    // ---- linear L3-warming sweep of BOTH tables (102.4 MB total) ----
    // Perfectly coalesced 16B/lane grid-stride; ~6-7 iters/table/thread.
    // acc kept alive by empty asm so the loads aren't DCE'd; no stores.
    {
        float acc = 0.f;
        const int gtid = blockIdx.x * 256 + tid;   // 0..NTHR-1
        for (int i = gtid; i < TBL4; i += NTHR) {
            float4 v = in4[i];
            acc += v.x + v.y + v.z + v.w;
        }
        for (int i = gtid; i < TBL4; i += NTHR) {
            float4 v = out4[i];
            acc += v.x + v.y + v.z + v.w;
        }
        asm volatile("" : : "v"(acc));             // keep sweep live (rule #17)
    }
    __builtin_amdgcn_sched_barrier(0);             // pin phase boundary

    // ---- stage all 21 row-gathers into registers (now mostly L3 hits) ----
    float4 cr[CWIN];
#pragma unroll
    for (int c = 0; c < CWIN; ++c) {
        const int idx = __shfl(myIdx, c, 32);      // broadcast within half
        cr[c] = in4[(idx << 5) + sub];             // idx*32 float4s
    }
    float4 ov[K_NEG + 1];
#pragma unroll
    for (int k = 0; k <= K_NEG; ++k) {
        const int lanesrc = (k == 0) ? 2 * CWIN : (CWIN + k - 1);
        const int idx = __shfl(myIdx, lanesrc, 32);
        ov[k] = out4[(idx << 5) + sub];
    }
    __builtin_amdgcn_sched_barrier(0);             // all 21 loads issued before use

    // ---- context mean (lane-partial over dims 4*sub..4*sub+3) ----
    float4 cm = make_float4(0.f, 0.f, 0.f, 0.f);
#pragma unroll
    for (int c = 0; c < CWIN; ++c) {
        cm.x += cr[c].x; cm.y += cr[c].y; cm.z += cr[c].z; cm.w += cr[c].w;
    }
    cm.x *= (1.0f / CWIN); cm.y *= (1.0f / CWIN);
    cm.z *= (1.0f / CWIN); cm.w *= (1.0f / CWIN);

    // ---- lane-partial scores ----
    float s[K_NEG + 1];
#pragma unroll
    for (int k = 0; k <= K_NEG; ++k)
        s[k] = cm.x * ov[k].x + cm.y * ov[k].y + cm.z * ov[k].z + cm.w * ov[k].w;

    // ---- butterfly reduce within the 32-lane half (5 stages) ----
#pragma unroll
    for (int j = 0; j <= K_NEG; ++j) {
        float x = s[j];
#pragma unroll
        for (int off = 16; off > 0; off >>= 1)
            x += __shfl_xor(x, off, 64);   // offsets <32 stay within each half
        s[j] = x;
    }

    // ---- per-b loss ----
    float l = __logf(1.0f / (1.0f + __expf(-s[0])) + EPS_F);       // pos
#pragma unroll
    for (int k = 1; k <= K_NEG; ++k)
        l += __logf(1.0f / (1.0f + __expf(s[k])) + EPS_F);         // neg

    // ---- block reduce: 8 per-b losses -> 1 partial (plain store, no atomics)
    __shared__ float lpart[BPB];
    if (sub == 0) lpart[halfId] = l;
    __syncthreads();
    if (tid == 0) {
        float p8 = 0.f;
#pragma unroll
        for (int i = 0; i < BPB; ++i) p8 += lpart[i];
        partials[blockIdx.x] = p8;
    }
}

__global__ __launch_bounds__(256) void finalize_kernel(
    const float* __restrict__ partials,    // NBLK floats
    float*       __restrict__ out)
{
    const int tid  = threadIdx.x;
    const int lane = tid & 63;
    const int wave = tid >> 6;

    float x = 0.f;
#pragma unroll
    for (int j = 0; j < NBLK / 256; ++j)
        x += partials[tid + 256 * j];      // coalesced, 8 KB total

#pragma unroll
    for (int off = 32; off > 0; off >>= 1)
        x += __shfl_xor(x, off, 64);

    __shared__ float part[4];
    if (lane == 0) part[wave] = x;
    __syncthreads();
    if (tid == 0)
        out[0] = -(part[0] + part[1] + part[2] + part[3]) * (1.0f / B_TOT);
}

extern "C" void kernel_launch(void* const* d_in, const int* in_sizes, int n_in,
                              void* d_out, int out_size, void* d_ws, size_t ws_size,
                              hipStream_t stream) {
    const int*   context   = (const int*)  d_in[0];
    const int*   target    = (const int*)  d_in[1];
    const int*   negatives = (const int*)  d_in[2];
    const float* in_emb    = (const float*)d_in[3];
    const float* out_emb   = (const float*)d_in[4];
    float*       out       = (float*)d_out;
    float*       partials  = (float*)d_ws;   // NBLK floats; fully written each call

    cbow_loss_kernel<<<NBLK, 256, 0, stream>>>(
        context, target, negatives, in_emb, out_emb, partials);
    finalize_kernel<<<1, 256, 0, stream>>>(partials, out);
}

// Round 6
// 142.176 us; speedup vs baseline: 1.0386x; 1.0386x over previous
//
#include <hip/hip_runtime.h>

// CBOW negative-sampling loss.
// Inputs (setup_inputs order):
//   d_in[0] context   [B, C]  int32
//   d_in[1] target    [B]     int32
//   d_in[2] negatives [B, K]  int32
//   d_in[3] in_emb    [V, D]  f32
//   d_in[4] out_emb   [V, D]  f32
// Output: scalar f32 = -mean_b( log(sig(pos)+eps) + sum_k log(sig(-neg_k)+eps) )
//
// R9: occupancy experiment. R8's L3-sweep reverted (it ADDED 49 MB of DRAM
// traffic and 10 us: no grid sync -> early gathers still missed; sweep
// bytes not free). R7's forced-MLP was null (and VGPR=48 shows staging
// never happened anyway) -> sched_barriers dropped. Remaining lever:
// launch_bounds(256,4) capped us at 16 waves/CU (50%), observed 37-53%,
// and 2048 blocks ran as TWO sequential rounds of 4 blocks/CU. With
// launch_bounds(256,8) and VGPR=36 <= 64, all 8 blocks/CU are co-resident:
// one round, 2x outstanding misses per CU (better DRAM bank overlap),
// no inter-round tail. Gather path otherwise identical to R3.

#define VOCAB  100000
#define DIM    128
#define B_TOT  16384
#define CWIN   10
#define K_NEG  10
#define EPS_F  1e-9f

#define BPB    8               // b's per 256-thread block (8 half-waves)
#define NBLK   (B_TOT / BPB)   // 2048 blocks = 256 CUs x 8 blocks, one round

__global__ __launch_bounds__(256, 8) void cbow_loss_kernel(
    const int*   __restrict__ context,
    const int*   __restrict__ target,
    const int*   __restrict__ negatives,
    const float* __restrict__ in_emb,
    const float* __restrict__ out_emb,
    float*       __restrict__ partials)    // NBLK floats in ws
{
    const int tid    = threadIdx.x;
    const int halfId = tid >> 5;           // 0..7
    const int sub    = tid & 31;           // lane within half-wave
    const int b      = blockIdx.x * BPB + halfId;

    const float4* in4  = (const float4*)in_emb;
    const float4* out4 = (const float4*)out_emb;

    // ---- ONE predicated load fetches all 21 indices for this half-wave ----
    // lanes 0..9  -> context[b*10+sub]
    // lanes 10..19-> negatives[b*10+(sub-10)]
    // lane  20    -> target[b]
    int myIdx = 0;
    {
        const int* p  = target;
        int        off = b;
        if (sub < CWIN)                 { p = context;   off = b * CWIN + sub; }
        else if (sub < 2 * CWIN)        { p = negatives; off = b * K_NEG + (sub - CWIN); }
        if (sub <= 2 * CWIN) myIdx = p[off];
    }

    // ---- 21 row-gathers (natural codegen; TLP supplies the MLP) ----
    float4 cr[CWIN];
#pragma unroll
    for (int c = 0; c < CWIN; ++c) {
        const int idx = __shfl(myIdx, c, 32);            // broadcast within half
        cr[c] = in4[(idx << 5) + sub];                   // idx*32 float4s
    }
    float4 ov[K_NEG + 1];
#pragma unroll
    for (int k = 0; k <= K_NEG; ++k) {
        const int lanesrc = (k == 0) ? 2 * CWIN : (CWIN + k - 1);
        const int idx = __shfl(myIdx, lanesrc, 32);
        ov[k] = out4[(idx << 5) + sub];
    }

    // ---- context mean (lane-partial over dims 4*sub..4*sub+3) ----
    float4 cm = make_float4(0.f, 0.f, 0.f, 0.f);
#pragma unroll
    for (int c = 0; c < CWIN; ++c) {
        cm.x += cr[c].x; cm.y += cr[c].y; cm.z += cr[c].z; cm.w += cr[c].w;
    }
    cm.x *= (1.0f / CWIN); cm.y *= (1.0f / CWIN);
    cm.z *= (1.0f / CWIN); cm.w *= (1.0f / CWIN);

    // ---- lane-partial scores ----
    float s[K_NEG + 1];
#pragma unroll
    for (int k = 0; k <= K_NEG; ++k)
        s[k] = cm.x * ov[k].x + cm.y * ov[k].y + cm.z * ov[k].z + cm.w * ov[k].w;

    // ---- butterfly reduce within the 32-lane half (5 stages) ----
#pragma unroll
    for (int j = 0; j <= K_NEG; ++j) {
        float x = s[j];
#pragma unroll
        for (int off = 16; off > 0; off >>= 1)
            x += __shfl_xor(x, off, 64);   // offsets <32 stay within each half
        s[j] = x;
    }

    // ---- per-b loss ----
    float l = __logf(1.0f / (1.0f + __expf(-s[0])) + EPS_F);       // pos
#pragma unroll
    for (int k = 1; k <= K_NEG; ++k)
        l += __logf(1.0f / (1.0f + __expf(s[k])) + EPS_F);         // neg

    // ---- block reduce: 8 per-b losses -> 1 partial (plain store, no atomics)
    __shared__ float lpart[BPB];
    if (sub == 0) lpart[halfId] = l;
    __syncthreads();
    if (tid == 0) {
        float p8 = 0.f;
#pragma unroll
        for (int i = 0; i < BPB; ++i) p8 += lpart[i];
        partials[blockIdx.x] = p8;
    }
}

__global__ __launch_bounds__(256) void finalize_kernel(
    const float* __restrict__ partials,    // NBLK floats
    float*       __restrict__ out)
{
    const int tid  = threadIdx.x;
    const int lane = tid & 63;
    const int wave = tid >> 6;

    float x = 0.f;
#pragma unroll
    for (int j = 0; j < NBLK / 256; ++j)
        x += partials[tid + 256 * j];      // coalesced, 8 KB total

#pragma unroll
    for (int off = 32; off > 0; off >>= 1)
        x += __shfl_xor(x, off, 64);

    __shared__ float part[4];
    if (lane == 0) part[wave] = x;
    __syncthreads();
    if (tid == 0)
        out[0] = -(part[0] + part[1] + part[2] + part[3]) * (1.0f / B_TOT);
}

extern "C" void kernel_launch(void* const* d_in, const int* in_sizes, int n_in,
                              void* d_out, int out_size, void* d_ws, size_t ws_size,
                              hipStream_t stream) {
    const int*   context   = (const int*)  d_in[0];
    const int*   target    = (const int*)  d_in[1];
    const int*   negatives = (const int*)  d_in[2];
    const float* in_emb    = (const float*)d_in[3];
    const float* out_emb   = (const float*)d_in[4];
    float*       out       = (float*)d_out;
    float*       partials  = (float*)d_ws;   // NBLK floats; fully written each call

    cbow_loss_kernel<<<NBLK, 256, 0, stream>>>(
        context, target, negatives, in_emb, out_emb, partials);
    finalize_kernel<<<1, 256, 0, stream>>>(partials, out);
}

// Round 7
// 130.216 us; speedup vs baseline: 1.1340x; 1.0918x over previous
//
#include <hip/hip_runtime.h>

// CBOW negative-sampling loss.
// Inputs (setup_inputs order):
//   d_in[0] context   [B, C]  int32
//   d_in[1] target    [B]     int32
//   d_in[2] negatives [B, K]  int32
//   d_in[3] in_emb    [V, D]  f32
//   d_in[4] out_emb   [V, D]  f32
// Output: scalar f32 = -mean_b( log(sig(pos)+eps) + sum_k log(sig(-neg_k)+eps) )
//
// R10: revert to best-measured config (R3/R7 structure, 131.0 us).
// Ledger of falsified levers for this problem:
//   - fusion w/ ACQ_REL atomics (R4): -96us, buffer_wbl2/inv kills L2 reuse
//   - fusion w/ relaxed atomics (R6): -32us, 2048 same-line RMWs x ~35ns
//     serialize at the coherence point (74us kernel)
//   - forced 21-deep MLP via sched_barrier (R7): null -> TLP already
//     saturates the memory path
//   - linear L3-warming sweep (R8): +10us, no grid sync means early gathers
//     still miss; sweep bytes not free
//   - 8 blocks/CU occupancy (R9): null duration, +9MB fetch (concurrent
//     same-row misses don't merge across XCD L2s)
// Main kernel is at the compulsory-traffic floor: FETCH == unique-row
// footprint (~84 MB); rate ~2.2-2.6 TB/s == random-512B DRAM regime.
// Half-wave (32 lanes) per b, one fully-coalesced 512B row load per gather;
// 21 indices via one predicated load + __shfl broadcast; butterfly reduce;
// per-block LDS reduce -> 2048 partials (8 KB); tiny finalize kernel.

#define VOCAB  100000
#define DIM    128
#define B_TOT  16384
#define CWIN   10
#define K_NEG  10
#define EPS_F  1e-9f

#define BPB    8               // b's per 256-thread block (8 half-waves)
#define NBLK   (B_TOT / BPB)   // 2048 blocks

__global__ __launch_bounds__(256, 4) void cbow_loss_kernel(
    const int*   __restrict__ context,
    const int*   __restrict__ target,
    const int*   __restrict__ negatives,
    const float* __restrict__ in_emb,
    const float* __restrict__ out_emb,
    float*       __restrict__ partials)    // NBLK floats in ws
{
    const int tid    = threadIdx.x;
    const int halfId = tid >> 5;           // 0..7
    const int sub    = tid & 31;           // lane within half-wave
    const int b      = blockIdx.x * BPB + halfId;

    const float4* in4  = (const float4*)in_emb;
    const float4* out4 = (const float4*)out_emb;

    // ---- ONE predicated load fetches all 21 indices for this half-wave ----
    // lanes 0..9  -> context[b*10+sub]
    // lanes 10..19-> negatives[b*10+(sub-10)]
    // lane  20    -> target[b]
    int myIdx = 0;
    {
        const int* p  = target;
        int        off = b;
        if (sub < CWIN)                 { p = context;   off = b * CWIN + sub; }
        else if (sub < 2 * CWIN)        { p = negatives; off = b * K_NEG + (sub - CWIN); }
        if (sub <= 2 * CWIN) myIdx = p[off];
    }

    // ---- 21 row-gathers (natural codegen; TLP supplies the MLP) ----
    float4 cr[CWIN];
#pragma unroll
    for (int c = 0; c < CWIN; ++c) {
        const int idx = __shfl(myIdx, c, 32);            // broadcast within half
        cr[c] = in4[(idx << 5) + sub];                   // idx*32 float4s
    }
    float4 ov[K_NEG + 1];
#pragma unroll
    for (int k = 0; k <= K_NEG; ++k) {
        const int lanesrc = (k == 0) ? 2 * CWIN : (CWIN + k - 1);
        const int idx = __shfl(myIdx, lanesrc, 32);
        ov[k] = out4[(idx << 5) + sub];
    }

    // ---- context mean (lane-partial over dims 4*sub..4*sub+3) ----
    float4 cm = make_float4(0.f, 0.f, 0.f, 0.f);
#pragma unroll
    for (int c = 0; c < CWIN; ++c) {
        cm.x += cr[c].x; cm.y += cr[c].y; cm.z += cr[c].z; cm.w += cr[c].w;
    }
    cm.x *= (1.0f / CWIN); cm.y *= (1.0f / CWIN);
    cm.z *= (1.0f / CWIN); cm.w *= (1.0f / CWIN);

    // ---- lane-partial scores ----
    float s[K_NEG + 1];
#pragma unroll
    for (int k = 0; k <= K_NEG; ++k)
        s[k] = cm.x * ov[k].x + cm.y * ov[k].y + cm.z * ov[k].z + cm.w * ov[k].w;

    // ---- butterfly reduce within the 32-lane half (5 stages) ----
#pragma unroll
    for (int j = 0; j <= K_NEG; ++j) {
        float x = s[j];
#pragma unroll
        for (int off = 16; off > 0; off >>= 1)
            x += __shfl_xor(x, off, 64);   // offsets <32 stay within each half
        s[j] = x;
    }

    // ---- per-b loss ----
    float l = __logf(1.0f / (1.0f + __expf(-s[0])) + EPS_F);       // pos
#pragma unroll
    for (int k = 1; k <= K_NEG; ++k)
        l += __logf(1.0f / (1.0f + __expf(s[k])) + EPS_F);         // neg

    // ---- block reduce: 8 per-b losses -> 1 partial (plain store, no atomics)
    __shared__ float lpart[BPB];
    if (sub == 0) lpart[halfId] = l;
    __syncthreads();
    if (tid == 0) {
        float p8 = 0.f;
#pragma unroll
        for (int i = 0; i < BPB; ++i) p8 += lpart[i];
        partials[blockIdx.x] = p8;
    }
}

__global__ __launch_bounds__(256) void finalize_kernel(
    const float* __restrict__ partials,    // NBLK floats
    float*       __restrict__ out)
{
    const int tid  = threadIdx.x;
    const int lane = tid & 63;
    const int wave = tid >> 6;

    float x = 0.f;
#pragma unroll
    for (int j = 0; j < NBLK / 256; ++j)
        x += partials[tid + 256 * j];      // coalesced, 8 KB total

#pragma unroll
    for (int off = 32; off > 0; off >>= 1)
        x += __shfl_xor(x, off, 64);

    __shared__ float part[4];
    if (lane == 0) part[wave] = x;
    __syncthreads();
    if (tid == 0)
        out[0] = -(part[0] + part[1] + part[2] + part[3]) * (1.0f / B_TOT);
}

extern "C" void kernel_launch(void* const* d_in, const int* in_sizes, int n_in,
                              void* d_out, int out_size, void* d_ws, size_t ws_size,
                              hipStream_t stream) {
    const int*   context   = (const int*)  d_in[0];
    const int*   target    = (const int*)  d_in[1];
    const int*   negatives = (const int*)  d_in[2];
    const float* in_emb    = (const float*)d_in[3];
    const float* out_emb   = (const float*)d_in[4];
    float*       out       = (float*)d_out;
    float*       partials  = (float*)d_ws;   // NBLK floats; fully written each call

    cbow_loss_kernel<<<NBLK, 256, 0, stream>>>(
        context, target, negatives, in_emb, out_emb, partials);
    finalize_kernel<<<1, 256, 0, stream>>>(partials, out);
}